// Round 3
// baseline (54.718 us; speedup 1.0000x reference)
//
#include <hip/hip_runtime.h>
#include <stdint.h>

typedef unsigned short ushort_t;
typedef short short8 __attribute__((ext_vector_type(8)));
typedef float f32x4 __attribute__((ext_vector_type(4)));

#define CIN   64
#define COUT  128
#define BATCH 16
#define LPIX  1024               // 32*32
#define NTOT  (BATCH*LPIX)       // 16384
#define KTOT  5184               // 9 * 576
#define C2N   576                // CIN*9 features; c2 = f*64 + i (f-major!)
#define PIXN  (BATCH*34*34)      // 18496 padded pixels
#define WROW  KTOT               // ushorts per Cout row
#define NSTEP 81                 // 9 basis-slices x 9 taps
#define PART_ELEMS (NTOT*COUT)   // 2,097,152

// workspace layout (bytes)
#define FEAT_BYTES (PIXN*C2N*2)            // 21,307,392
#define W_OFF      FEAT_BYTES
#define W_BYTES    (COUT*KTOT*2)           // 1,327,104
#define PART_OFF   (W_OFF + W_BYTES)
#define PART_BYTES (PART_ELEMS*4)          // 8,388,608
#define WS_NEED2   ((size_t)(PART_OFF + 1*PART_BYTES))
#define WS_NEED4   ((size_t)(PART_OFF + 3*PART_BYTES))

#define WAITVM(n) asm volatile("s_waitcnt vmcnt(" #n ")" ::: "memory")
#define BARRIER() asm volatile("s_barrier" ::: "memory")

__device__ __forceinline__ ushort_t to_bf16(float f) {
  union { float f; uint32_t u; } v; v.f = f;
  uint32_t r = (v.u + 0x7fffu + ((v.u >> 16) & 1u)) >> 16;
  return (ushort_t)r;
}

// H_0..H_7 (physicists') of x, plus silu(x) at [8]
__device__ __forceinline__ void basis9(float x, float* o) {
  float hm = 1.f, h = 2.f * x;
  o[0] = hm; o[1] = h;
#pragma unroll
  for (int n = 1; n < 7; ++n) {
    float nx = 2.f * x * h - 2.f * (float)n * hm;
    hm = h; h = nx;
    o[n + 1] = nx;
  }
  o[8] = x / (1.f + __expf(-x));
}

__device__ __forceinline__ void load16(const void* g, void* l) {
  __builtin_amdgcn_global_load_lds(
      (const __attribute__((address_space(1))) uint32_t*)g,
      (__attribute__((address_space(3))) uint32_t*)l, 16, 0, 0);
}

// -------- feature map: feat[pix(b,34,34)][f*64+i] bf16, coalesced stores --
__global__ void feat_kernel(const float* __restrict__ x, ushort_t* __restrict__ feat) {
  const int t = threadIdx.x;
  const int lane = t & 63;                      // = cin index i
  const int pg = blockIdx.x * 4 + (t >> 6);     // padded pixel id
  if (pg >= PIXN) return;
  const int xx = pg % 34;
  const int rest = pg / 34;
  const int yy = rest % 34;
  const int bb = rest / 34;
  float v = 0.f;
  if (xx >= 1 && xx <= 32 && yy >= 1 && yy <= 32)
    v = x[((bb * CIN + lane) * 32 + (yy - 1)) * 32 + (xx - 1)];
  float o[9];
  basis9(v, o);
  ushort_t* dst = feat + (size_t)pg * C2N + lane;
#pragma unroll
  for (int f = 0; f < 9; ++f) dst[f * 64] = to_bf16(o[f]);   // 128B/wave stores
}

// -------- weight matrix, swizzled, written in storage order (coalesced) ---
// logical W[m][k], k = kk*576 + f*64 + i ; 16B chunk (k>>3) xored with m&7
__global__ void prep_w_kernel(const float* __restrict__ wb, const float* __restrict__ wsp,
                              const float* __restrict__ cc, ushort_t* __restrict__ W) {
  const int idx = blockIdx.x * 256 + threadIdx.x;  // storage index
  if (idx >= COUT * KTOT) return;
  const int m = idx / WROW;
  const int pos = idx - m * WROW;
  const int k = (pos & ~63) | ((((pos >> 3) & 7) ^ (m & 7)) << 3) | (pos & 7);
  const int kk = k / C2N;
  const int r = k - kk * C2N;
  const int f = r >> 6;
  const int i = r & 63;
  const int base = (i * COUT + m) * 9 + kk;
  const float val = (f < 8) ? wsp[base] * cc[base * 8 + f] : wb[base];
  W[idx] = to_bf16(val);
}

// -------- GEMM: counted-vmcnt pipeline, halo-reuse B staging --------------
// out[n][m] = sum_s W[m][k(s)] * feat[pix(n,tap(s))][c2(s)]
// step s in [0,81): c2-slice = s/9 (basis f), tap kk = s%9. Halo staged
// once per slice; A triple-buffered, prefetch depth 2, vmcnt never 0
// in steady state (8 = two 4-load A batches in flight).
template <int KS>
__global__ __launch_bounds__(256, 2) void gemm_kernel(const ushort_t* __restrict__ feat,
                                                      const ushort_t* __restrict__ W,
                                                      float* __restrict__ out,
                                                      float* __restrict__ part) {
  __shared__ ushort_t Ab[3][8192];     // [m=128][k=64], swizzled, triple buf
  __shared__ ushort_t Hb[1792 * 8];    // halo: 224 px x 64 feats (204 used)
  const int t = threadIdx.x;
  const int lane = t & 63;
  const int wave = t >> 6;
  const int wm = wave >> 1, wn = wave & 1;

  // XCD-chunked remap, nb-major: consecutive logicals share the N-tile.
  const int logical = (blockIdx.x & 7) * (gridDim.x >> 3) + (blockIdx.x >> 3);
  const int nb = logical / KS;
  const int slice = logical - nb * KS;
  const int lo = (slice * NSTEP) / KS;
  const int hi = ((slice + 1) * NSTEP) / KS;

  const int b  = nb >> 3;               // image
  const int y0 = (nb & 7) * 4;          // padded rows y0..y0+5
  const int pixbase = (b * 34 + y0) * 34;

  const char* Wb = (const char*)W;
  const char* Fb = (const char*)feat;

  f32x4 acc[4][4];
#pragma unroll
  for (int a = 0; a < 4; ++a)
#pragma unroll
    for (int c = 0; c < 4; ++c) acc[a][c] = (f32x4)0.f;

  auto stage_halo = [&](int c2s) {      // 7 loads/thread
    const char* base = Fb + (size_t)pixbase * (C2N * 2) + c2s * 128;
#pragma unroll
    for (int it = 0; it < 7; ++it) {
      const int q = it * 256 + t;           // chunk id, 224 px x 8 chunks
      const int hp = q >> 3, sl = q & 7;
      load16(base + hp * (C2N * 2) + ((sl ^ (hp & 7)) << 4), &Hb[q * 8]);
    }
  };

  auto stageA = [&](int ib, int s) {    // 4 loads/thread
    const int c64 = (s % 9) * 9 + (s / 9);  // 64-wide K-chunk index in W rows
#pragma unroll
    for (int q = 0; q < 4; ++q) {
      const int idx16 = q * 256 + t;
      const int m = idx16 >> 3, ccn = idx16 & 7;
      load16(Wb + m * (WROW * 2) + c64 * 128 + ccn * 16, &Ab[ib][idx16 * 8]);
    }
  };

  auto compute = [&](int ib, int s) {
    const int kk = s % 9;
    const int dy = kk / 3, dx = kk - dy * 3;
#pragma unroll
    for (int ks = 0; ks < 2; ++ks) {
      short8 av[4], bv[4];
      const int slot = ks * 4 + (lane >> 4);
#pragma unroll
      for (int mf = 0; mf < 4; ++mf) {
        const int row = wm * 64 + mf * 16 + (lane & 15);
        av[mf] = *(const short8*)&Ab[ib][row * 64 + ((slot ^ (row & 7)) << 3)];
      }
#pragma unroll
      for (int nf = 0; nf < 4; ++nf) {
        const int nl = wn * 64 + nf * 16 + (lane & 15);
        const int hp = ((nl >> 5) + dy) * 34 + (nl & 31) + dx;
        bv[nf] = *(const short8*)&Hb[hp * 64 + ((slot ^ (hp & 7)) << 3)];
      }
      __builtin_amdgcn_s_setprio(1);
#pragma unroll
      for (int mf = 0; mf < 4; ++mf)
#pragma unroll
        for (int nf = 0; nf < 4; ++nf)
          acc[mf][nf] = __builtin_amdgcn_mfma_f32_16x16x32_bf16(av[mf], bv[nf],
                                                                acc[mf][nf], 0, 0, 0);
      __builtin_amdgcn_s_setprio(0);
    }
  };

  // prologue: H(first slice) oldest, then A(lo), A(lo+1)
  stage_halo(lo / 9);
  stageA(0, lo);
  if (lo + 1 < hi) stageA(1, lo + 1);

  for (int s = lo; s < hi; ++s) {
    const int ib = (s - lo) % 3;
    if (s + 2 < hi) stageA((s - lo + 2) % 3, s + 2);
    // issue order so far: ..., A(s+1), [H(slice(s)) if s is slice-first], A(s+2)
    const int younger = ((s % 9) == 0 && s > lo)
                            ? (s + 2 < hi ? 1 : 0)
                            : ((s + 1 < hi ? 1 : 0) + (s + 2 < hi ? 1 : 0));
    if (younger == 2) WAITVM(8);
    else if (younger == 1) WAITVM(4);
    else WAITVM(0);
    BARRIER();
    compute(ib, s);
    BARRIER();
    if (s + 1 < hi && ((s + 1) % 9) == 0) stage_halo((s + 1) / 9);
  }

  float* dst = slice ? (part + (size_t)(slice - 1) * PART_ELEMS) : out;
#pragma unroll
  for (int mf = 0; mf < 4; ++mf)
#pragma unroll
    for (int nf = 0; nf < 4; ++nf)
#pragma unroll
      for (int rg = 0; rg < 4; ++rg) {
        const int m = wm * 64 + mf * 16 + (lane >> 4) * 4 + rg;
        const int n = nb * 128 + wn * 64 + nf * 16 + (lane & 15);
        const int bb = n >> 10, ll = n & 1023;
        dst[(bb * COUT + m) * LPIX + ll] = acc[mf][nf][rg];
      }
}

template <int NP>
__global__ void add_kernel(float* __restrict__ out, const float* __restrict__ part) {
  const int i = (blockIdx.x * 256 + threadIdx.x) * 4;
  f32x4 a = *(const f32x4*)&out[i];
#pragma unroll
  for (int j = 0; j < NP; ++j)
    a += *(const f32x4*)&part[(size_t)j * PART_ELEMS + i];
  *(f32x4*)&out[i] = a;
}

// ---------------- fallback (only if ws too small): direct evaluation -----
__global__ void naive_kernel(const float* __restrict__ x, const float* __restrict__ wb,
                             const float* __restrict__ wsp, const float* __restrict__ cc,
                             float* __restrict__ out) {
  const int idx = blockIdx.x * 256 + threadIdx.x;
  if (idx >= BATCH * COUT * LPIX) return;
  const int l = idx & 1023, o = (idx >> 10) & 127, b = idx >> 17;
  const int h = l >> 5, w = l & 31;
  float acc = 0.f;
  for (int i = 0; i < CIN; ++i)
    for (int kk = 0; kk < 9; ++kk) {
      const int yy = h + kk / 3 - 1, xx = w + kk % 3 - 1;
      const float v = (yy >= 0 && yy < 32 && xx >= 0 && xx < 32)
                          ? x[((b * CIN + i) * 32 + yy) * 32 + xx] : 0.f;
      float ftr[9];
      basis9(v, ftr);
      const int base = (i * COUT + o) * 9 + kk;
      const float* cp = cc + base * 8;
      float dot = 0.f;
#pragma unroll
      for (int f = 0; f < 8; ++f) dot += cp[f] * ftr[f];
      acc += wsp[base] * dot + wb[base] * ftr[8];
    }
  out[idx] = acc;
}

extern "C" void kernel_launch(void* const* d_in, const int* in_sizes, int n_in,
                              void* d_out, int out_size, void* d_ws, size_t ws_size,
                              hipStream_t stream) {
  const float* x  = (const float*)d_in[0];
  const float* wb = (const float*)d_in[1];
  const float* wsp = (const float*)d_in[2];
  const float* cc = (const float*)d_in[3];
  float* out = (float*)d_out;

  if (ws_size < WS_NEED2) {
    naive_kernel<<<(BATCH * COUT * LPIX + 255) / 256, 256, 0, stream>>>(x, wb, wsp, cc, out);
    return;
  }

  char* ws = (char*)d_ws;
  ushort_t* feat = (ushort_t*)ws;
  ushort_t* W    = (ushort_t*)(ws + W_OFF);
  float* part    = (float*)(ws + PART_OFF);

  feat_kernel<<<PIXN / 4, 256, 0, stream>>>(x, feat);
  prep_w_kernel<<<(COUT * KTOT) / 256, 256, 0, stream>>>(wb, wsp, cc, W);
  if (ws_size >= WS_NEED4) {
    gemm_kernel<4><<<128 * 4, 256, 0, stream>>>(feat, W, out, part);
    add_kernel<3><<<PART_ELEMS / 1024, 256, 0, stream>>>(out, part);
  } else {
    gemm_kernel<2><<<128 * 2, 256, 0, stream>>>(feat, W, out, part);
    add_kernel<1><<<PART_ELEMS / 1024, 256, 0, stream>>>(out, part);
  }
}

// Round 4
// 53.390 us; speedup vs baseline: 1.0249x; 1.0249x over previous
//
#include <hip/hip_runtime.h>
#include <stdint.h>

typedef unsigned short ushort_t;
typedef short short8 __attribute__((ext_vector_type(8)));
typedef float f32x4 __attribute__((ext_vector_type(4)));

#define CIN   64
#define COUT  128
#define BATCH 16
#define LPIX  1024               // 32*32
#define NTOT  (BATCH*LPIX)       // 16384
#define KTOT  5184               // 9 * 576
#define C2N   576                // CIN*9 features; c2 = f*64 + i (f-major)
#define PIXN  (BATCH*34*34)      // 18496 padded pixels
#define WROW  KTOT               // ushorts per Cout row
#define NSTEP 81                 // 27 groups (dy,c2s) x 3 dx
#define PART_ELEMS (NTOT*COUT)   // 2,097,152
#define FEAT_BLOCKS (PIXN/4)     // 4624
#define PREP_BLOCKS (COUT*KTOT/256) // 2592

// workspace layout (bytes)
#define FEAT_BYTES (PIXN*C2N*2)            // 21,307,392
#define W_OFF      FEAT_BYTES
#define W_BYTES    (COUT*KTOT*2)           // 1,327,104
#define PART_OFF   (W_OFF + W_BYTES)
#define PART_BYTES (PART_ELEMS*4)          // 8,388,608
#define WS_NEED(KS) ((size_t)(PART_OFF + (size_t)((KS)-1)*PART_BYTES))

__device__ __forceinline__ ushort_t to_bf16(float f) {
  union { float f; uint32_t u; } v; v.f = f;
  uint32_t r = (v.u + 0x7fffu + ((v.u >> 16) & 1u)) >> 16;
  return (ushort_t)r;
}

// H_0..H_7 (physicists') of x, plus silu(x) at [8]
__device__ __forceinline__ void basis9(float x, float* o) {
  float hm = 1.f, h = 2.f * x;
  o[0] = hm; o[1] = h;
#pragma unroll
  for (int n = 1; n < 7; ++n) {
    float nx = 2.f * x * h - 2.f * (float)n * hm;
    hm = h; h = nx;
    o[n + 1] = nx;
  }
  o[8] = x / (1.f + __expf(-x));
}

__device__ __forceinline__ void load16(const void* g, void* l) {
  __builtin_amdgcn_global_load_lds(
      (const __attribute__((address_space(1))) uint32_t*)g,
      (__attribute__((address_space(3))) uint32_t*)l, 16, 0, 0);
}

// -------- fused prep: feat map (coalesced) + weight matrix ----------------
// feat[pix(b,34,34)][f*64+i] bf16 ; W[m][k] k=kk*576+f*64+i, 16B-chunk
// (k>>3) xored with m&7, stored in storage order (coalesced writes).
__global__ void prep_kernel(const float* __restrict__ x, ushort_t* __restrict__ feat,
                            const float* __restrict__ wb, const float* __restrict__ wsp,
                            const float* __restrict__ cc, ushort_t* __restrict__ W) {
  const int t = threadIdx.x;
  if (blockIdx.x < FEAT_BLOCKS) {
    const int lane = t & 63;                      // = cin index i
    const int pg = blockIdx.x * 4 + (t >> 6);     // padded pixel id
    const int xx = pg % 34;
    const int rest = pg / 34;
    const int yy = rest % 34;
    const int bb = rest / 34;
    float v = 0.f;
    if (xx >= 1 && xx <= 32 && yy >= 1 && yy <= 32)
      v = x[((bb * CIN + lane) * 32 + (yy - 1)) * 32 + (xx - 1)];
    float o[9];
    basis9(v, o);
    ushort_t* dst = feat + (size_t)pg * C2N + lane;
#pragma unroll
    for (int f = 0; f < 9; ++f) dst[f * 64] = to_bf16(o[f]);  // 128B/wave stores
  } else {
    const int idx = (blockIdx.x - FEAT_BLOCKS) * 256 + t;     // storage index
    const int m = idx / WROW;
    const int pos = idx - m * WROW;
    const int k = (pos & ~63) | ((((pos >> 3) & 7) ^ (m & 7)) << 3) | (pos & 7);
    const int kk = k / C2N;
    const int r = k - kk * C2N;
    const int f = r >> 6;
    const int i = r & 63;
    const int base = (i * COUT + m) * 9 + kk;
    const float val = (f < 8) ? wsp[base] * cc[base * 8 + f] : wb[base];
    W[idx] = to_bf16(val);
  }
}

// -------- GEMM: 4-row circular halo, 3 blocks/CU ---------------------------
// step s: group g=s/3 -> (dy=g/9, c2s=g%9), dx=s%3, tap kk=dy*3+dx.
// Halo: rows y0+dy..y0+dy+3 of slice c2s, slot=(row-y0)&3, restaged per group.
// A [m=128][k=64] double-buffered. K-chunk c64 = kk*9 + c2s.
template <int KS>
__global__ __launch_bounds__(256, 3) void gemm_kernel(const ushort_t* __restrict__ feat,
                                                      const ushort_t* __restrict__ W,
                                                      float* __restrict__ out,
                                                      float* __restrict__ part) {
  __shared__ ushort_t Ab[2][8192];     // 32 KB: [m=128][k=64], swizzled, dbuf
  __shared__ ushort_t Hb[4 * 34 * 64]; // 17 KB: 4 row-slots x 34 px x 64 feats
  const int t = threadIdx.x;
  const int lane = t & 63;
  const int wave = t >> 6;
  const int wm = wave >> 1, wn = wave & 1;

  // XCD-chunked remap, nb-major: consecutive logicals share the N-tile.
  const int logical = (blockIdx.x & 7) * (gridDim.x >> 3) + (blockIdx.x >> 3);
  const int nb = logical / KS;
  const int slice = logical - nb * KS;
  const int lo = (slice * NSTEP) / KS;
  const int hi = ((slice + 1) * NSTEP) / KS;

  const int b  = nb >> 3;               // image
  const int y0 = (nb & 7) * 4;          // padded rows y0..y0+5 touched
  const int pixbase = (b * 34 + y0) * 34;

  const char* Wb = (const char*)W;
  const char* Fb = (const char*)feat;

  f32x4 acc[4][4];
#pragma unroll
  for (int a = 0; a < 4; ++a)
#pragma unroll
    for (int c = 0; c < 4; ++c) acc[a][c] = (f32x4)0.f;

  // stage 4 rows (slice c2s, rows y0+dy..y0+dy+3) into slots (dy+rl)&3.
  auto stage_halo = [&](int g) {
    const int dy = g / 9, c2s = g - dy * 9;
#pragma unroll
    for (int it = 0; it < 5; ++it) {
      const int q = it * 256 + t;             // dest 16B-chunk id in Hb
      if (q < 1088) {                         // 136 L x 8 chunks
        const int L = q >> 3;                 // slot*34 + px
        const int slot = L / 34;
        const int px = L - slot * 34;
        const int rl = (slot - dy) & 3;       // local row within group
        const int pix = pixbase + (dy + rl) * 34 + px;
        const int sl = (q & 7) ^ (L & 7);     // source-side swizzle
        load16(Fb + (size_t)pix * (C2N * 2) + c2s * 128 + (sl << 4), &Hb[q * 8]);
      }
    }
  };

  auto stageA = [&](int p, int s) {
    const int g = s / 3;
    const int dx = s - g * 3;
    const int dy = g / 9, c2s = g - dy * 9;
    const int c64 = (dy * 3 + dx) * 9 + c2s;  // 64-wide K-chunk in W rows
#pragma unroll
    for (int q = 0; q < 4; ++q) {
      const int idx16 = q * 256 + t;
      const int m = idx16 >> 3, ccn = idx16 & 7;
      load16(Wb + m * (WROW * 2) + c64 * 128 + ccn * 16, &Ab[p][idx16 * 8]);
    }
  };

  auto compute = [&](int p, int dy, int dx) {
#pragma unroll
    for (int ks = 0; ks < 2; ++ks) {
      short8 av[4], bv[4];
      const int kslot = ks * 4 + (lane >> 4);
#pragma unroll
      for (int mf = 0; mf < 4; ++mf) {
        const int row = wm * 64 + mf * 16 + (lane & 15);
        av[mf] = *(const short8*)&Ab[p][row * 64 + ((kslot ^ (row & 7)) << 3)];
      }
#pragma unroll
      for (int nf = 0; nf < 4; ++nf) {
        const int nl = wn * 64 + nf * 16 + (lane & 15);
        const int L = (((nl >> 5) + dy) & 3) * 34 + (nl & 31) + dx;
        bv[nf] = *(const short8*)&Hb[L * 64 + ((kslot ^ (L & 7)) << 3)];
      }
#pragma unroll
      for (int mf = 0; mf < 4; ++mf)
#pragma unroll
        for (int nf = 0; nf < 4; ++nf)
          acc[mf][nf] = __builtin_amdgcn_mfma_f32_16x16x32_bf16(av[mf], bv[nf],
                                                                acc[mf][nf], 0, 0, 0);
    }
  };

  stage_halo(lo / 3);
  stageA(0, lo);
  __syncthreads();
  for (int s = lo; s < hi; ++s) {
    const int p = (s - lo) & 1;
    const int g = s / 3;
    const int dx = s - g * 3;
    const int dy = g / 9;
    const bool newgrp = (dx == 0) && (s > lo);
    if (newgrp) stage_halo(g);                // old halo dead since last barrier
    if (s + 1 < hi) stageA(p ^ 1, s + 1);
    if (newgrp) __syncthreads();              // halo DMA must land before compute
    compute(p, dy, dx);
    __syncthreads();
  }

  float* dst = slice ? (part + (size_t)(slice - 1) * PART_ELEMS) : out;
#pragma unroll
  for (int mf = 0; mf < 4; ++mf)
#pragma unroll
    for (int nf = 0; nf < 4; ++nf)
#pragma unroll
      for (int rg = 0; rg < 4; ++rg) {
        const int m = wm * 64 + mf * 16 + (lane >> 4) * 4 + rg;
        const int n = nb * 128 + wn * 64 + nf * 16 + (lane & 15);
        const int bb = n >> 10, ll = n & 1023;
        dst[(bb * COUT + m) * LPIX + ll] = acc[mf][nf][rg];
      }
}

template <int NP>
__global__ void add_kernel(float* __restrict__ out, const float* __restrict__ part) {
  const int i = (blockIdx.x * 256 + threadIdx.x) * 4;
  f32x4 a = *(const f32x4*)&out[i];
#pragma unroll
  for (int j = 0; j < NP; ++j)
    a += *(const f32x4*)&part[(size_t)j * PART_ELEMS + i];
  *(f32x4*)&out[i] = a;
}

// ---------------- fallback (only if ws too small): direct evaluation -----
__global__ void naive_kernel(const float* __restrict__ x, const float* __restrict__ wb,
                             const float* __restrict__ wsp, const float* __restrict__ cc,
                             float* __restrict__ out) {
  const int idx = blockIdx.x * 256 + threadIdx.x;
  if (idx >= BATCH * COUT * LPIX) return;
  const int l = idx & 1023, o = (idx >> 10) & 127, b = idx >> 17;
  const int h = l >> 5, w = l & 31;
  float acc = 0.f;
  for (int i = 0; i < CIN; ++i)
    for (int kk = 0; kk < 9; ++kk) {
      const int yy = h + kk / 3 - 1, xx = w + kk % 3 - 1;
      const float v = (yy >= 0 && yy < 32 && xx >= 0 && xx < 32)
                          ? x[((b * CIN + i) * 32 + yy) * 32 + xx] : 0.f;
      float ftr[9];
      basis9(v, ftr);
      const int base = (i * COUT + o) * 9 + kk;
      const float* cp = cc + base * 8;
      float dot = 0.f;
#pragma unroll
      for (int f = 0; f < 8; ++f) dot += cp[f] * ftr[f];
      acc += wsp[base] * dot + wb[base] * ftr[8];
    }
  out[idx] = acc;
}

extern "C" void kernel_launch(void* const* d_in, const int* in_sizes, int n_in,
                              void* d_out, int out_size, void* d_ws, size_t ws_size,
                              hipStream_t stream) {
  const float* x  = (const float*)d_in[0];
  const float* wb = (const float*)d_in[1];
  const float* wsp = (const float*)d_in[2];
  const float* cc = (const float*)d_in[3];
  float* out = (float*)d_out;

  if (ws_size < WS_NEED(2)) {
    naive_kernel<<<(BATCH * COUT * LPIX + 255) / 256, 256, 0, stream>>>(x, wb, wsp, cc, out);
    return;
  }

  char* ws = (char*)d_ws;
  ushort_t* feat = (ushort_t*)ws;
  ushort_t* W    = (ushort_t*)(ws + W_OFF);
  float* part    = (float*)(ws + PART_OFF);

  prep_kernel<<<FEAT_BLOCKS + PREP_BLOCKS, 256, 0, stream>>>(x, feat, wb, wsp, cc, W);
  if (ws_size >= WS_NEED(6)) {
    gemm_kernel<6><<<128 * 6, 256, 0, stream>>>(feat, W, out, part);
    add_kernel<5><<<PART_ELEMS / 1024, 256, 0, stream>>>(out, part);
  } else {
    gemm_kernel<2><<<128 * 2, 256, 0, stream>>>(feat, W, out, part);
    add_kernel<1><<<PART_ELEMS / 1024, 256, 0, stream>>>(out, part);
  }
}